// Round 15
// baseline (1110.051 us; speedup 1.0000x reference)
//
#include <hip/hip_runtime.h>
#include <hip/hip_bf16.h>
#include <hip/hip_cooperative_groups.h>

namespace cg = cooperative_groups;

#define NN 50000
#define NE 800000
#define DF 128
#define NSL 128      // dst slices for bucket sort
#define SLN 391      // nodes per slice (128*391 = 50048 >= NN)
#define CAP 8192     // bucket capacity per slice (avg 6250)
#define ECHUNK 1563  // edges per bucket block (512*1563 >= NE)
#define F2BB 6346    // f2b blocks: (NN*DF + 6*DF*DF)/4/256
#define BBLK 512     // bucket blocks
#define AGG_VB 12500 // agg virtual blocks (4 nodes each)
#define GEMM_VB 782  // gemm virtual blocks (64 rows each)

typedef __bf16 bf16x8 __attribute__((ext_vector_type(8)));
typedef float f32x4 __attribute__((ext_vector_type(4)));

__device__ __forceinline__ unsigned short f32_to_bf16_rne(float f) {
    unsigned int u = __float_as_uint(f);
    u += 0x7fffu + ((u >> 16) & 1u);
    return (unsigned short)(u >> 16);
}

__device__ __forceinline__ unsigned int pack_bf16x2(float lo, float hi) {
    return (unsigned int)f32_to_bf16_rne(lo) | ((unsigned int)f32_to_bf16_rne(hi) << 16);
}

// ---------------- tiny zero ----------------
__global__ void k_zero(int* __restrict__ p, int n) {
    int i = threadIdx.x;
    if (i < n) p[i] = 0;
}

// ------- fused: bucket(512 blocks) + f2b convert(6346 blocks) --------------
__global__ __launch_bounds__(256) void k_build1(const int* __restrict__ src, const int* __restrict__ dst,
                                                int* __restrict__ gcur, uint2* __restrict__ bucket,
                                                const float* __restrict__ feats,
                                                const float* __restrict__ w0, const float* __restrict__ w1,
                                                const float* __restrict__ w2, const float* __restrict__ w3,
                                                const float* __restrict__ w4, const float* __restrict__ w5,
                                                unsigned short* __restrict__ h_bf,
                                                unsigned short* __restrict__ Wb) {
    int t = threadIdx.x;
    if (blockIdx.x < BBLK) {
        __shared__ int cnt[NSL];
        __shared__ int rb[NSL];
        for (int j = t; j < NSL; j += 256) cnt[j] = 0;
        __syncthreads();
        int base = blockIdx.x * ECHUNK;
        int end = base + ECHUNK;
        if (end > NE) end = NE;
        for (int i = base + t; i < end; i += 256) atomicAdd(&cnt[dst[i] / SLN], 1);
        __syncthreads();
        for (int j = t; j < NSL; j += 256) rb[j] = atomicAdd(&gcur[j], cnt[j]);
        __syncthreads();
        for (int j = t; j < NSL; j += 256) cnt[j] = rb[j];  // reuse as write cursor
        __syncthreads();
        for (int i = base + t; i < end; i += 256) {
            int d = dst[i];
            int s = d / SLN;
            int pos = atomicAdd(&cnt[s], 1);
            bucket[s * CAP + pos] = make_uint2((unsigned)src[i], (unsigned)d);
        }
    } else {
        int i = ((blockIdx.x - BBLK) * 256 + t) * 4;
        const float* fsrc;
        unsigned short* dstp;
        if (i < NN * DF) {
            fsrc = feats + i;
            dstp = h_bf + i;
        } else {
            int j = i - NN * DF;
            if (j >= 6 * DF * DF) return;
            int w = j >> 14;
            int o = j & 16383;
            const float* ws[6] = {w0, w1, w2, w3, w4, w5};
            fsrc = ws[w] + o;
            dstp = Wb + w * DF * DF + o;
        }
        float4 v = *reinterpret_cast<const float4*>(fsrc);
        ushort4 r;
        r.x = f32_to_bf16_rne(v.x);
        r.y = f32_to_bf16_rne(v.y);
        r.z = f32_to_bf16_rne(v.z);
        r.w = f32_to_bf16_rne(v.w);
        *reinterpret_cast<ushort4*>(dstp) = r;
    }
}

// One block per slice: own CSR base, degree count, LDS scan, edge placement.
__global__ __launch_bounds__(256) void k_cslice(const uint2* __restrict__ bucket, const int* __restrict__ gcur,
                                                int* __restrict__ col, int* __restrict__ row_ptr,
                                                float* __restrict__ inv_deg) {
    __shared__ int sdeg[512];
    __shared__ int scur[512];
    __shared__ int shcb;
    int s = blockIdx.x;
    int t = threadIdx.x;
    int nbase = s * SLN;
    int ncnt = NN - nbase;
    if (ncnt > SLN) ncnt = SLN;
    int ecnt = gcur[s];
    int eb = s * CAP;
    if (t == 0) {
        int acc = 0;
        for (int i = 0; i < s; ++i) acc += gcur[i];
        shcb = acc;
        if (s == NSL - 1) row_ptr[NN] = acc + ecnt;  // == NE
    }
    sdeg[t] = 0;
    sdeg[t + 256] = 0;
    __syncthreads();
    int cb = shcb;
    for (int e = t; e < ecnt; e += 256) atomicAdd(&sdeg[bucket[eb + e].y - nbase], 1);
    __syncthreads();
    int d0 = sdeg[t], d1 = sdeg[t + 256];
    for (int off = 1; off < 512; off <<= 1) {
        int v0 = (t >= off) ? sdeg[t - off] : 0;
        int v1 = (t + 256 >= off) ? sdeg[t + 256 - off] : 0;
        __syncthreads();
        sdeg[t] += v0;
        sdeg[t + 256] += v1;
        __syncthreads();
    }
    int e0 = sdeg[t] - d0, e1 = sdeg[t + 256] - d1;  // exclusive scan
    scur[t] = e0;
    scur[t + 256] = e1;
    if (t < ncnt) {
        row_ptr[nbase + t] = cb + e0;
        inv_deg[nbase + t] = 1.0f / (float)(d0 > 1 ? d0 : 1);
    }
    if (t + 256 < ncnt) {
        row_ptr[nbase + t + 256] = cb + e1;
        inv_deg[nbase + t + 256] = 1.0f / (float)(d1 > 1 ? d1 : 1);
    }
    __syncthreads();
    for (int e = t; e < ecnt; e += 256) {
        uint2 pr = bucket[eb + e];
        int p = atomicAdd(&scur[pr.y - nbase], 1);
        col[cb + p] = (int)pr.x;
    }
}

// ---------------- cooperative 3-layer loop ---------------------------------
// Co-resident grid; per layer: grid-stride agg phase (full occupancy),
// grid.sync, grid-stride gemm phase (ping-pong h write), grid.sync.
__global__ __launch_bounds__(256, 8) void k_layers(unsigned short* __restrict__ H0,
                                                   unsigned short* __restrict__ H1,
                                                   unsigned short* __restrict__ Agg,
                                                   const int* __restrict__ row_ptr,
                                                   const int* __restrict__ col,
                                                   const float* __restrict__ inv_deg,
                                                   const unsigned short* __restrict__ Wb,
                                                   const float* __restrict__ b0,
                                                   const float* __restrict__ b1,
                                                   const float* __restrict__ b2,
                                                   float* __restrict__ Dout) {
    cg::grid_group grid = cg::this_grid();
    int wid = threadIdx.x >> 6;
    int lane = threadIdx.x & 63;
    int g = lane >> 4;
    int l15 = lane & 15;

    unsigned short* hcur = H0;
    unsigned short* hnext = H1;

    for (int l = 0; l < 3; ++l) {
        // ---- agg phase ----
        {
            int off = l15 * 8;
            for (int vb = blockIdx.x; vb < AGG_VB; vb += gridDim.x) {
                int node = vb * 4 + wid;
                if (node >= NN) continue;
                int s = row_ptr[node], e = row_ptr[node + 1];
                float a[8];
#pragma unroll
                for (int k = 0; k < 8; ++k) a[k] = 0.f;
                for (int base = s; base < e; base += 64) {
                    int rem = e - base;
                    if (rem > 64) rem = 64;
                    int cl = (lane < rem) ? col[base + lane] : 0;
                    for (int jj = 0; jj < rem; jj += 16) {
#pragma unroll
                        for (int u = 0; u < 4; ++u) {
                            int idx = jj + 4 * u + g;
                            int c = __shfl(cl, idx, 64);
                            if (idx < rem) {
                                uint4 v = *reinterpret_cast<const uint4*>(hcur + (size_t)c * DF + off);
                                a[0] += __uint_as_float(v.x << 16);
                                a[1] += __uint_as_float(v.x & 0xffff0000u);
                                a[2] += __uint_as_float(v.y << 16);
                                a[3] += __uint_as_float(v.y & 0xffff0000u);
                                a[4] += __uint_as_float(v.z << 16);
                                a[5] += __uint_as_float(v.z & 0xffff0000u);
                                a[6] += __uint_as_float(v.w << 16);
                                a[7] += __uint_as_float(v.w & 0xffff0000u);
                            }
                        }
                    }
                }
#pragma unroll
                for (int k = 0; k < 8; ++k) {
                    a[k] += __shfl_xor(a[k], 16, 64);
                    a[k] += __shfl_xor(a[k], 32, 64);
                }
                if (g == 0) {
                    float iv = inv_deg[node];
                    uint4 r;
                    r.x = pack_bf16x2(a[0] * iv, a[1] * iv);
                    r.y = pack_bf16x2(a[2] * iv, a[3] * iv);
                    r.z = pack_bf16x2(a[4] * iv, a[5] * iv);
                    r.w = pack_bf16x2(a[6] * iv, a[7] * iv);
                    *reinterpret_cast<uint4*>(Agg + (size_t)node * DF + off) = r;
                }
            }
        }
        grid.sync();

        // ---- gemm phase: out = relu(hcur@Ws^T + Agg@Wn^T + bias) ----
        {
            const unsigned short* Ws = Wb + l * 2 * DF * DF;
            const float* bias = (l == 0) ? b0 : (l == 1) ? b1 : b2;
            bool last = (l == 2);
            int lk = g * 8;
            int colb = wid * 32;
            for (int vb = blockIdx.x; vb < GEMM_VB; vb += gridDim.x) {
                int brow = vb * 64;
                f32x4 zero = {0.f, 0.f, 0.f, 0.f};
                f32x4 acc[4][2];
#pragma unroll
                for (int m = 0; m < 4; ++m) {
                    acc[m][0] = zero;
                    acc[m][1] = zero;
                }
#pragma unroll
                for (int ph = 0; ph < 2; ++ph) {
                    const unsigned short* Ap = ph ? Agg : hcur;
                    const unsigned short* Wp = Ws + ph * (DF * DF);
#pragma unroll
                    for (int ks = 0; ks < 4; ++ks) {
                        int kb = ks * 32 + lk;
                        bf16x8 bfr0 = *reinterpret_cast<const bf16x8*>(Wp + (colb + l15) * DF + kb);
                        bf16x8 bfr1 = *reinterpret_cast<const bf16x8*>(Wp + (colb + 16 + l15) * DF + kb);
#pragma unroll
                        for (int m = 0; m < 4; ++m) {
                            int r = brow + m * 16 + l15;
                            if (r >= NN) r = NN - 1;
                            bf16x8 afr = *reinterpret_cast<const bf16x8*>(Ap + (size_t)r * DF + kb);
                            acc[m][0] = __builtin_amdgcn_mfma_f32_16x16x32_bf16(afr, bfr0, acc[m][0], 0, 0, 0);
                            acc[m][1] = __builtin_amdgcn_mfma_f32_16x16x32_bf16(afr, bfr1, acc[m][1], 0, 0, 0);
                        }
                    }
                }
                int rb = g * 4;
#pragma unroll
                for (int q = 0; q < 2; ++q) {
                    int o = colb + q * 16 + l15;
                    float bv = bias[o];
#pragma unroll
                    for (int m = 0; m < 4; ++m) {
#pragma unroll
                        for (int j = 0; j < 4; ++j) {
                            int r = brow + m * 16 + rb + j;
                            if (r < NN) {
                                float v = fmaxf(acc[m][q][j] + bv, 0.f);
                                if (last) Dout[(size_t)r * DF + o] = v;
                                else hnext[(size_t)r * DF + o] = f32_to_bf16_rne(v);
                            }
                        }
                    }
                }
            }
        }
        grid.sync();

        unsigned short* t = hcur;
        hcur = hnext;
        hnext = t;
    }
}

extern "C" void kernel_launch(void* const* d_in, const int* in_sizes, int n_in,
                              void* d_out, int out_size, void* d_ws, size_t ws_size,
                              hipStream_t stream) {
    const float* feats = (const float*)d_in[0];
    const int* src = (const int*)d_in[1];
    const int* dst = (const int*)d_in[2];

    char* ws = (char*)d_ws;
    unsigned short* h_bf = (unsigned short*)(ws);                 // 12,800,000 B
    unsigned short* agg_bf = (unsigned short*)(ws + 12800000);    // 12,800,000 B
    uint2* bucket = (uint2*)(ws + 12800000);                      // 8,388,608 B (overlaid: build-phase only)
    unsigned short* Wb = (unsigned short*)(ws + 25600000);        // 196,608 B
    int* row_ptr = (int*)(ws + 25796608);                         // 200,008 B
    float* inv_deg = (float*)(ws + 25996616);                     // 200,000 B
    int* col = (int*)(ws + 26196616);                             // 3,200,000 B
    int* gcur = (int*)(ws + 29396616);                            // 512 B
    unsigned short* h1 = (unsigned short*)(ws + 29400064);        // 12,800,000 B (ping-pong)

    k_zero<<<1, 128, 0, stream>>>(gcur, NSL);
    k_build1<<<BBLK + F2BB, 256, 0, stream>>>(
        src, dst, gcur, bucket, feats,
        (const float*)d_in[3], (const float*)d_in[4], (const float*)d_in[6],
        (const float*)d_in[7], (const float*)d_in[9], (const float*)d_in[10], h_bf, Wb);
    k_cslice<<<NSL, 256, 0, stream>>>(bucket, gcur, col, row_ptr, inv_deg);

    int maxb = 8;
    hipOccupancyMaxActiveBlocksPerMultiprocessor(&maxb, k_layers, 256, 0);
    int grid = maxb * 256;
    if (grid > 2048) grid = 2048;
    if (grid < 256) grid = 256;

    float* dout = (float*)d_out;
    const float* b0 = (const float*)d_in[5];
    const float* b1 = (const float*)d_in[8];
    const float* b2 = (const float*)d_in[11];
    void* args[] = {&h_bf, &h1, &agg_bf, &row_ptr, &col, &inv_deg, &Wb, &b0, &b1, &b2, &dout};
    hipLaunchCooperativeKernel((void*)k_layers, dim3(grid), dim3(256), args, 0, stream);
}

// Round 16
// 237.385 us; speedup vs baseline: 4.6762x; 4.6762x over previous
//
#include <hip/hip_runtime.h>
#include <hip/hip_bf16.h>

#define NN 50000
#define NE 800000
#define DF 128
#define NSL 128      // dst slices for bucket sort
#define SLN 391      // nodes per slice (128*391 = 50048 >= NN)
#define CAP 8192     // bucket capacity per slice (avg 6250)
#define ECHUNK 1563  // edges per bucket block (512*1563 >= NE)
#define F2BB 6346    // f2b blocks: (NN*DF + 6*DF*DF)/4/256
#define BBLK 512     // bucket blocks

typedef __bf16 bf16x8 __attribute__((ext_vector_type(8)));
typedef float f32x4 __attribute__((ext_vector_type(4)));

__device__ __forceinline__ unsigned short f32_to_bf16_rne(float f) {
    unsigned int u = __float_as_uint(f);
    u += 0x7fffu + ((u >> 16) & 1u);
    return (unsigned short)(u >> 16);
}

__device__ __forceinline__ unsigned int pack_bf16x2(float lo, float hi) {
    return (unsigned int)f32_to_bf16_rne(lo) | ((unsigned int)f32_to_bf16_rne(hi) << 16);
}

// ---------------- tiny zero ----------------
__global__ void k_zero(int* __restrict__ p, int n) {
    int i = threadIdx.x;
    if (i < n) p[i] = 0;
}

// ------- fused: bucket(512 blocks) + f2b convert(6346 blocks) --------------
__global__ __launch_bounds__(256) void k_build1(const int* __restrict__ src, const int* __restrict__ dst,
                                                int* __restrict__ gcur, uint2* __restrict__ bucket,
                                                const float* __restrict__ feats,
                                                const float* __restrict__ w0, const float* __restrict__ w1,
                                                const float* __restrict__ w2, const float* __restrict__ w3,
                                                const float* __restrict__ w4, const float* __restrict__ w5,
                                                unsigned short* __restrict__ h_bf,
                                                unsigned short* __restrict__ Wb) {
    int t = threadIdx.x;
    if (blockIdx.x < BBLK) {
        __shared__ int cnt[NSL];
        __shared__ int rb[NSL];
        for (int j = t; j < NSL; j += 256) cnt[j] = 0;
        __syncthreads();
        int base = blockIdx.x * ECHUNK;
        int end = base + ECHUNK;
        if (end > NE) end = NE;
        for (int i = base + t; i < end; i += 256) atomicAdd(&cnt[dst[i] / SLN], 1);
        __syncthreads();
        for (int j = t; j < NSL; j += 256) rb[j] = atomicAdd(&gcur[j], cnt[j]);
        __syncthreads();
        for (int j = t; j < NSL; j += 256) cnt[j] = rb[j];  // reuse as write cursor
        __syncthreads();
        for (int i = base + t; i < end; i += 256) {
            int d = dst[i];
            int s = d / SLN;
            int pos = atomicAdd(&cnt[s], 1);
            bucket[s * CAP + pos] = make_uint2((unsigned)src[i], (unsigned)d);
        }
    } else {
        int i = ((blockIdx.x - BBLK) * 256 + t) * 4;
        const float* fsrc;
        unsigned short* dstp;
        if (i < NN * DF) {
            fsrc = feats + i;
            dstp = h_bf + i;
        } else {
            int j = i - NN * DF;
            if (j >= 6 * DF * DF) return;
            int w = j >> 14;
            int o = j & 16383;
            const float* ws[6] = {w0, w1, w2, w3, w4, w5};
            fsrc = ws[w] + o;
            dstp = Wb + w * DF * DF + o;
        }
        float4 v = *reinterpret_cast<const float4*>(fsrc);
        ushort4 r;
        r.x = f32_to_bf16_rne(v.x);
        r.y = f32_to_bf16_rne(v.y);
        r.z = f32_to_bf16_rne(v.z);
        r.w = f32_to_bf16_rne(v.w);
        *reinterpret_cast<ushort4*>(dstp) = r;
    }
}

// One block per slice: own CSR base, degree count, LDS scan, edge placement.
__global__ __launch_bounds__(256) void k_cslice(const uint2* __restrict__ bucket, const int* __restrict__ gcur,
                                                int* __restrict__ col, int* __restrict__ row_ptr,
                                                float* __restrict__ inv_deg) {
    __shared__ int sdeg[512];
    __shared__ int scur[512];
    __shared__ int shcb;
    int s = blockIdx.x;
    int t = threadIdx.x;
    int nbase = s * SLN;
    int ncnt = NN - nbase;
    if (ncnt > SLN) ncnt = SLN;
    int ecnt = gcur[s];
    int eb = s * CAP;
    if (t == 0) {
        int acc = 0;
        for (int i = 0; i < s; ++i) acc += gcur[i];
        shcb = acc;
        if (s == NSL - 1) row_ptr[NN] = acc + ecnt;  // == NE
    }
    sdeg[t] = 0;
    sdeg[t + 256] = 0;
    __syncthreads();
    int cb = shcb;
    for (int e = t; e < ecnt; e += 256) atomicAdd(&sdeg[bucket[eb + e].y - nbase], 1);
    __syncthreads();
    int d0 = sdeg[t], d1 = sdeg[t + 256];
    for (int off = 1; off < 512; off <<= 1) {
        int v0 = (t >= off) ? sdeg[t - off] : 0;
        int v1 = (t + 256 >= off) ? sdeg[t + 256 - off] : 0;
        __syncthreads();
        sdeg[t] += v0;
        sdeg[t + 256] += v1;
        __syncthreads();
    }
    int e0 = sdeg[t] - d0, e1 = sdeg[t + 256] - d1;  // exclusive scan
    scur[t] = e0;
    scur[t + 256] = e1;
    if (t < ncnt) {
        row_ptr[nbase + t] = cb + e0;
        inv_deg[nbase + t] = 1.0f / (float)(d0 > 1 ? d0 : 1);
    }
    if (t + 256 < ncnt) {
        row_ptr[nbase + t + 256] = cb + e1;
        inv_deg[nbase + t + 256] = 1.0f / (float)(d1 > 1 ? d1 : 1);
    }
    __syncthreads();
    for (int e = t; e < ecnt; e += 256) {
        uint2 pr = bucket[eb + e];
        int p = atomicAdd(&scur[pr.y - nbase], 1);
        col[cb + p] = (int)pr.x;
    }
}

// ---------------- aggregation v4: col-prefetch + 16 gathers in flight ------
__global__ __launch_bounds__(256) void k_agg(const unsigned short* __restrict__ H,
                                             const int* __restrict__ row_ptr, const int* __restrict__ col,
                                             const float* __restrict__ inv_deg,
                                             unsigned short* __restrict__ Agg, int n) {
    int wid = threadIdx.x >> 6;
    int lane = threadIdx.x & 63;
    int node = blockIdx.x * 4 + wid;
    if (node >= n) return;
    int s = row_ptr[node], e = row_ptr[node + 1];
    int g = lane >> 4;
    int l = lane & 15;
    int off = l * 8;  // 8 bf16 per lane

    float a[8];
#pragma unroll
    for (int k = 0; k < 8; ++k) a[k] = 0.f;

    for (int base = s; base < e; base += 64) {
        int rem = e - base;
        if (rem > 64) rem = 64;
        int cl = (lane < rem) ? col[base + lane] : 0;
        for (int jj = 0; jj < rem; jj += 16) {
#pragma unroll
            for (int u = 0; u < 4; ++u) {
                int idx = jj + 4 * u + g;
                int c = __shfl(cl, idx, 64);
                if (idx < rem) {
                    uint4 v = *reinterpret_cast<const uint4*>(H + (size_t)c * DF + off);
                    a[0] += __uint_as_float(v.x << 16);
                    a[1] += __uint_as_float(v.x & 0xffff0000u);
                    a[2] += __uint_as_float(v.y << 16);
                    a[3] += __uint_as_float(v.y & 0xffff0000u);
                    a[4] += __uint_as_float(v.z << 16);
                    a[5] += __uint_as_float(v.z & 0xffff0000u);
                    a[6] += __uint_as_float(v.w << 16);
                    a[7] += __uint_as_float(v.w & 0xffff0000u);
                }
            }
        }
    }

#pragma unroll
    for (int k = 0; k < 8; ++k) {
        a[k] += __shfl_xor(a[k], 16, 64);
        a[k] += __shfl_xor(a[k], 32, 64);
    }

    if (g == 0) {
        float iv = inv_deg[node];
        uint4 r;
        r.x = pack_bf16x2(a[0] * iv, a[1] * iv);
        r.y = pack_bf16x2(a[2] * iv, a[3] * iv);
        r.z = pack_bf16x2(a[4] * iv, a[5] * iv);
        r.w = pack_bf16x2(a[6] * iv, a[7] * iv);
        *reinterpret_cast<uint4*>(Agg + (size_t)node * DF + off) = r;
    }
}

// ------- fused GEMM, BM=32: out = relu(Hb@Ws^T + Ab@Wn^T + bias) -----------
// 32 rows/block -> 1563 blocks (~24 waves/CU) for latency hiding on the
// streamed A/Agg reads. 4 waves, wave w owns output cols [32w,32w+32).
// In-place safe: block writes only its own 32 rows, after __syncthreads.
__global__ __launch_bounds__(256) void k_gemm(const unsigned short* __restrict__ Hb,
                                              const unsigned short* __restrict__ Ab,
                                              const unsigned short* __restrict__ Wb,  // Ws | Wn (bf16)
                                              const float* __restrict__ bias,
                                              unsigned short* __restrict__ Hout,  // may alias Hb (or null)
                                              float* __restrict__ Fout,           // f32 out (or null)
                                              int n) {
    int brow = blockIdx.x * 32;
    int lane = threadIdx.x & 63;
    int wid = threadIdx.x >> 6;
    int l15 = lane & 15;
    int lk = (lane >> 4) * 8;
    int colb = wid * 32;

    f32x4 zero = {0.f, 0.f, 0.f, 0.f};
    f32x4 acc[2][2];
#pragma unroll
    for (int m = 0; m < 2; ++m) {
        acc[m][0] = zero;
        acc[m][1] = zero;
    }

#pragma unroll
    for (int ph = 0; ph < 2; ++ph) {
        const unsigned short* Ap = ph ? Ab : Hb;
        const unsigned short* Wp = Wb + ph * (DF * DF);
#pragma unroll
        for (int ks = 0; ks < 4; ++ks) {
            int kb = ks * 32 + lk;
            bf16x8 bfr0 = *reinterpret_cast<const bf16x8*>(Wp + (colb + l15) * DF + kb);
            bf16x8 bfr1 = *reinterpret_cast<const bf16x8*>(Wp + (colb + 16 + l15) * DF + kb);
#pragma unroll
            for (int m = 0; m < 2; ++m) {
                int r = brow + m * 16 + l15;
                if (r >= n) r = n - 1;
                bf16x8 afr = *reinterpret_cast<const bf16x8*>(Ap + (size_t)r * DF + kb);
                acc[m][0] = __builtin_amdgcn_mfma_f32_16x16x32_bf16(afr, bfr0, acc[m][0], 0, 0, 0);
                acc[m][1] = __builtin_amdgcn_mfma_f32_16x16x32_bf16(afr, bfr1, acc[m][1], 0, 0, 0);
            }
        }
    }

    __syncthreads();  // in-place safety: all waves' A reads complete before any store

    int rb = (lane >> 4) * 4;
#pragma unroll
    for (int q = 0; q < 2; ++q) {
        int o = colb + q * 16 + l15;
        float bv = bias[o];
#pragma unroll
        for (int m = 0; m < 2; ++m) {
#pragma unroll
            for (int j = 0; j < 4; ++j) {
                int r = brow + m * 16 + rb + j;
                if (r < n) {
                    float v = fmaxf(acc[m][q][j] + bv, 0.f);
                    if (Fout) Fout[(size_t)r * DF + o] = v;
                    else Hout[(size_t)r * DF + o] = f32_to_bf16_rne(v);
                }
            }
        }
    }
}

extern "C" void kernel_launch(void* const* d_in, const int* in_sizes, int n_in,
                              void* d_out, int out_size, void* d_ws, size_t ws_size,
                              hipStream_t stream) {
    const float* feats = (const float*)d_in[0];
    const int* src = (const int*)d_in[1];
    const int* dst = (const int*)d_in[2];
    const float* bias[3] = {(const float*)d_in[5], (const float*)d_in[8], (const float*)d_in[11]};

    char* ws = (char*)d_ws;
    unsigned short* h_bf = (unsigned short*)(ws);                 // 12,800,000 B
    unsigned short* agg_bf = (unsigned short*)(ws + 12800000);    // 12,800,000 B
    uint2* bucket = (uint2*)(ws + 12800000);                      // 8,388,608 B (overlaid: build-phase only)
    unsigned short* Wb = (unsigned short*)(ws + 25600000);        // 196,608 B
    int* row_ptr = (int*)(ws + 25796608);                         // 200,008 B
    float* inv_deg = (float*)(ws + 25996616);                     // 200,000 B
    int* col = (int*)(ws + 26196616);                             // 3,200,000 B
    int* gcur = (int*)(ws + 29396616);                            // 512 B

    k_zero<<<1, 128, 0, stream>>>(gcur, NSL);
    k_build1<<<BBLK + F2BB, 256, 0, stream>>>(
        src, dst, gcur, bucket, feats,
        (const float*)d_in[3], (const float*)d_in[4], (const float*)d_in[6],
        (const float*)d_in[7], (const float*)d_in[9], (const float*)d_in[10], h_bf, Wb);
    k_cslice<<<NSL, 256, 0, stream>>>(bucket, gcur, col, row_ptr, inv_deg);

    int gblk = (NN + 31) / 32;  // 1563
    for (int l = 0; l < 3; ++l) {
        k_agg<<<(NN + 3) / 4, 256, 0, stream>>>(h_bf, row_ptr, col, inv_deg, agg_bf, NN);
        const unsigned short* Wl = Wb + l * 2 * DF * DF;
        if (l < 2)
            k_gemm<<<gblk, 256, 0, stream>>>(h_bf, agg_bf, Wl, bias[l], h_bf, nullptr, NN);
        else
            k_gemm<<<gblk, 256, 0, stream>>>(h_bf, agg_bf, Wl, bias[l], nullptr, (float*)d_out, NN);
    }
}

// Round 17
// 232.849 us; speedup vs baseline: 4.7673x; 1.0195x over previous
//
#include <hip/hip_runtime.h>
#include <hip/hip_bf16.h>

#define NN 50000
#define NE 800000
#define DF 128
#define NSL 128      // dst slices for bucket sort
#define SLN 391      // nodes per slice (128*391 = 50048 >= NN)
#define CAP 8192     // bucket capacity per slice (avg 6250)
#define ECHUNK 1563  // edges per bucket block (512*1563 >= NE)
#define F2BB 6346    // f2b blocks: (NN*DF + 6*DF*DF)/4/256
#define BBLK 512     // bucket blocks

typedef __bf16 bf16x8 __attribute__((ext_vector_type(8)));
typedef float f32x4 __attribute__((ext_vector_type(4)));

__device__ __forceinline__ unsigned short f32_to_bf16_rne(float f) {
    unsigned int u = __float_as_uint(f);
    u += 0x7fffu + ((u >> 16) & 1u);
    return (unsigned short)(u >> 16);
}

__device__ __forceinline__ unsigned int pack_bf16x2(float lo, float hi) {
    return (unsigned int)f32_to_bf16_rne(lo) | ((unsigned int)f32_to_bf16_rne(hi) << 16);
}

// ---------------- tiny zero ----------------
__global__ void k_zero(int* __restrict__ p, int n) {
    int i = threadIdx.x;
    if (i < n) p[i] = 0;
}

// ------- fused: bucket(512 blocks) + f2b convert(6346 blocks) --------------
__global__ __launch_bounds__(256) void k_build1(const int* __restrict__ src, const int* __restrict__ dst,
                                                int* __restrict__ gcur, uint2* __restrict__ bucket,
                                                const float* __restrict__ feats,
                                                const float* __restrict__ w0, const float* __restrict__ w1,
                                                const float* __restrict__ w2, const float* __restrict__ w3,
                                                const float* __restrict__ w4, const float* __restrict__ w5,
                                                unsigned short* __restrict__ h_bf,
                                                unsigned short* __restrict__ Wb) {
    int t = threadIdx.x;
    if (blockIdx.x < BBLK) {
        __shared__ int cnt[NSL];
        __shared__ int rb[NSL];
        for (int j = t; j < NSL; j += 256) cnt[j] = 0;
        __syncthreads();
        int base = blockIdx.x * ECHUNK;
        int end = base + ECHUNK;
        if (end > NE) end = NE;
        for (int i = base + t; i < end; i += 256) atomicAdd(&cnt[dst[i] / SLN], 1);
        __syncthreads();
        for (int j = t; j < NSL; j += 256) rb[j] = atomicAdd(&gcur[j], cnt[j]);
        __syncthreads();
        for (int j = t; j < NSL; j += 256) cnt[j] = rb[j];  // reuse as write cursor
        __syncthreads();
        for (int i = base + t; i < end; i += 256) {
            int d = dst[i];
            int s = d / SLN;
            int pos = atomicAdd(&cnt[s], 1);
            bucket[s * CAP + pos] = make_uint2((unsigned)src[i], (unsigned)d);
        }
    } else {
        int i = ((blockIdx.x - BBLK) * 256 + t) * 4;
        const float* fsrc;
        unsigned short* dstp;
        if (i < NN * DF) {
            fsrc = feats + i;
            dstp = h_bf + i;
        } else {
            int j = i - NN * DF;
            if (j >= 6 * DF * DF) return;
            int w = j >> 14;
            int o = j & 16383;
            const float* ws[6] = {w0, w1, w2, w3, w4, w5};
            fsrc = ws[w] + o;
            dstp = Wb + w * DF * DF + o;
        }
        float4 v = *reinterpret_cast<const float4*>(fsrc);
        ushort4 r;
        r.x = f32_to_bf16_rne(v.x);
        r.y = f32_to_bf16_rne(v.y);
        r.z = f32_to_bf16_rne(v.z);
        r.w = f32_to_bf16_rne(v.w);
        *reinterpret_cast<ushort4*>(dstp) = r;
    }
}

// One block per slice: own CSR base, degree count, LDS scan, edge placement.
__global__ __launch_bounds__(256) void k_cslice(const uint2* __restrict__ bucket, const int* __restrict__ gcur,
                                                int* __restrict__ col, int* __restrict__ row_ptr,
                                                float* __restrict__ inv_deg) {
    __shared__ int sdeg[512];
    __shared__ int scur[512];
    __shared__ int shcb;
    int s = blockIdx.x;
    int t = threadIdx.x;
    int nbase = s * SLN;
    int ncnt = NN - nbase;
    if (ncnt > SLN) ncnt = SLN;
    int ecnt = gcur[s];
    int eb = s * CAP;
    if (t == 0) {
        int acc = 0;
        for (int i = 0; i < s; ++i) acc += gcur[i];
        shcb = acc;
        if (s == NSL - 1) row_ptr[NN] = acc + ecnt;  // == NE
    }
    sdeg[t] = 0;
    sdeg[t + 256] = 0;
    __syncthreads();
    int cb = shcb;
    for (int e = t; e < ecnt; e += 256) atomicAdd(&sdeg[bucket[eb + e].y - nbase], 1);
    __syncthreads();
    int d0 = sdeg[t], d1 = sdeg[t + 256];
    for (int off = 1; off < 512; off <<= 1) {
        int v0 = (t >= off) ? sdeg[t - off] : 0;
        int v1 = (t + 256 >= off) ? sdeg[t + 256 - off] : 0;
        __syncthreads();
        sdeg[t] += v0;
        sdeg[t + 256] += v1;
        __syncthreads();
    }
    int e0 = sdeg[t] - d0, e1 = sdeg[t + 256] - d1;  // exclusive scan
    scur[t] = e0;
    scur[t + 256] = e1;
    if (t < ncnt) {
        row_ptr[nbase + t] = cb + e0;
        inv_deg[nbase + t] = 1.0f / (float)(d0 > 1 ? d0 : 1);
    }
    if (t + 256 < ncnt) {
        row_ptr[nbase + t + 256] = cb + e1;
        inv_deg[nbase + t + 256] = 1.0f / (float)(d1 > 1 ? d1 : 1);
    }
    __syncthreads();
    for (int e = t; e < ecnt; e += 256) {
        uint2 pr = bucket[eb + e];
        int p = atomicAdd(&scur[pr.y - nbase], 1);
        col[cb + p] = (int)pr.x;
    }
}

// ---------------- aggregation v4: col-prefetch + 16 gathers in flight ------
__global__ __launch_bounds__(256) void k_agg(const unsigned short* __restrict__ H,
                                             const int* __restrict__ row_ptr, const int* __restrict__ col,
                                             const float* __restrict__ inv_deg,
                                             unsigned short* __restrict__ Agg, int n) {
    int wid = threadIdx.x >> 6;
    int lane = threadIdx.x & 63;
    int node = blockIdx.x * 4 + wid;
    if (node >= n) return;
    int s = row_ptr[node], e = row_ptr[node + 1];
    int g = lane >> 4;
    int l = lane & 15;
    int off = l * 8;  // 8 bf16 per lane

    float a[8];
#pragma unroll
    for (int k = 0; k < 8; ++k) a[k] = 0.f;

    for (int base = s; base < e; base += 64) {
        int rem = e - base;
        if (rem > 64) rem = 64;
        int cl = (lane < rem) ? col[base + lane] : 0;
        for (int jj = 0; jj < rem; jj += 16) {
#pragma unroll
            for (int u = 0; u < 4; ++u) {
                int idx = jj + 4 * u + g;
                int c = __shfl(cl, idx, 64);
                if (idx < rem) {
                    uint4 v = *reinterpret_cast<const uint4*>(H + (size_t)c * DF + off);
                    a[0] += __uint_as_float(v.x << 16);
                    a[1] += __uint_as_float(v.x & 0xffff0000u);
                    a[2] += __uint_as_float(v.y << 16);
                    a[3] += __uint_as_float(v.y & 0xffff0000u);
                    a[4] += __uint_as_float(v.z << 16);
                    a[5] += __uint_as_float(v.z & 0xffff0000u);
                    a[6] += __uint_as_float(v.w << 16);
                    a[7] += __uint_as_float(v.w & 0xffff0000u);
                }
            }
        }
    }

#pragma unroll
    for (int k = 0; k < 8; ++k) {
        a[k] += __shfl_xor(a[k], 16, 64);
        a[k] += __shfl_xor(a[k], 32, 64);
    }

    if (g == 0) {
        float iv = inv_deg[node];
        uint4 r;
        r.x = pack_bf16x2(a[0] * iv, a[1] * iv);
        r.y = pack_bf16x2(a[2] * iv, a[3] * iv);
        r.z = pack_bf16x2(a[4] * iv, a[5] * iv);
        r.w = pack_bf16x2(a[6] * iv, a[7] * iv);
        *reinterpret_cast<uint4*>(Agg + (size_t)node * DF + off) = r;
    }
}

// ---------------- fused GEMM BM=64: out = relu(Hb@Ws^T + Ab@Wn^T + bias) ----
// 64 rows/block, 4 waves, wave w owns output cols [32w,32w+32). K=256.
// In-place safe: block writes only its own 64 rows, after __syncthreads.
__global__ __launch_bounds__(256) void k_gemm(const unsigned short* __restrict__ Hb,
                                              const unsigned short* __restrict__ Ab,
                                              const unsigned short* __restrict__ Wb,  // Ws | Wn (bf16)
                                              const float* __restrict__ bias,
                                              unsigned short* __restrict__ Hout,  // may alias Hb (or null)
                                              float* __restrict__ Fout,           // f32 out (or null)
                                              int n) {
    int brow = blockIdx.x * 64;
    int lane = threadIdx.x & 63;
    int wid = threadIdx.x >> 6;
    int l15 = lane & 15;
    int lk = (lane >> 4) * 8;
    int colb = wid * 32;

    f32x4 zero = {0.f, 0.f, 0.f, 0.f};
    f32x4 acc[4][2];
#pragma unroll
    for (int m = 0; m < 4; ++m) {
        acc[m][0] = zero;
        acc[m][1] = zero;
    }

#pragma unroll
    for (int ph = 0; ph < 2; ++ph) {
        const unsigned short* Ap = ph ? Ab : Hb;
        const unsigned short* Wp = Wb + ph * (DF * DF);
#pragma unroll
        for (int ks = 0; ks < 4; ++ks) {
            int kb = ks * 32 + lk;
            bf16x8 bfr0 = *reinterpret_cast<const bf16x8*>(Wp + (colb + l15) * DF + kb);
            bf16x8 bfr1 = *reinterpret_cast<const bf16x8*>(Wp + (colb + 16 + l15) * DF + kb);
#pragma unroll
            for (int m = 0; m < 4; ++m) {
                int r = brow + m * 16 + l15;
                if (r >= n) r = n - 1;
                bf16x8 afr = *reinterpret_cast<const bf16x8*>(Ap + (size_t)r * DF + kb);
                acc[m][0] = __builtin_amdgcn_mfma_f32_16x16x32_bf16(afr, bfr0, acc[m][0], 0, 0, 0);
                acc[m][1] = __builtin_amdgcn_mfma_f32_16x16x32_bf16(afr, bfr1, acc[m][1], 0, 0, 0);
            }
        }
    }

    __syncthreads();  // in-place safety: all waves' A reads complete before any store

    int rb = (lane >> 4) * 4;
#pragma unroll
    for (int q = 0; q < 2; ++q) {
        int o = colb + q * 16 + l15;
        float bv = bias[o];
#pragma unroll
        for (int m = 0; m < 4; ++m) {
#pragma unroll
            for (int j = 0; j < 4; ++j) {
                int r = brow + m * 16 + rb + j;
                if (r < n) {
                    float v = fmaxf(acc[m][q][j] + bv, 0.f);
                    if (Fout) Fout[(size_t)r * DF + o] = v;
                    else Hout[(size_t)r * DF + o] = f32_to_bf16_rne(v);
                }
            }
        }
    }
}

extern "C" void kernel_launch(void* const* d_in, const int* in_sizes, int n_in,
                              void* d_out, int out_size, void* d_ws, size_t ws_size,
                              hipStream_t stream) {
    const float* feats = (const float*)d_in[0];
    const int* src = (const int*)d_in[1];
    const int* dst = (const int*)d_in[2];
    const float* bias[3] = {(const float*)d_in[5], (const float*)d_in[8], (const float*)d_in[11]};

    char* ws = (char*)d_ws;
    unsigned short* h_bf = (unsigned short*)(ws);                 // 12,800,000 B
    unsigned short* agg_bf = (unsigned short*)(ws + 12800000);    // 12,800,000 B
    uint2* bucket = (uint2*)(ws + 12800000);                      // 8,388,608 B (overlaid: build-phase only)
    unsigned short* Wb = (unsigned short*)(ws + 25600000);        // 196,608 B
    int* row_ptr = (int*)(ws + 25796608);                         // 200,008 B
    float* inv_deg = (float*)(ws + 25996616);                     // 200,000 B
    int* col = (int*)(ws + 26196616);                             // 3,200,000 B
    int* gcur = (int*)(ws + 29396616);                            // 512 B

    k_zero<<<1, 128, 0, stream>>>(gcur, NSL);
    k_build1<<<BBLK + F2BB, 256, 0, stream>>>(
        src, dst, gcur, bucket, feats,
        (const float*)d_in[3], (const float*)d_in[4], (const float*)d_in[6],
        (const float*)d_in[7], (const float*)d_in[9], (const float*)d_in[10], h_bf, Wb);
    k_cslice<<<NSL, 256, 0, stream>>>(bucket, gcur, col, row_ptr, inv_deg);

    int gblk = (NN + 63) / 64;  // 782
    for (int l = 0; l < 3; ++l) {
        k_agg<<<(NN + 3) / 4, 256, 0, stream>>>(h_bf, row_ptr, col, inv_deg, agg_bf, NN);
        const unsigned short* Wl = Wb + l * 2 * DF * DF;
        if (l < 2)
            k_gemm<<<gblk, 256, 0, stream>>>(h_bf, agg_bf, Wl, bias[l], h_bf, nullptr, NN);
        else
            k_gemm<<<gblk, 256, 0, stream>>>(h_bf, agg_bf, Wl, bias[l], nullptr, (float*)d_out, NN);
    }
}